// Round 10
// baseline (2320.485 us; speedup 1.0000x reference)
//
#include <hip/hip_runtime.h>
#include <math.h>

#define TPC 225
#define NCLS 224
#define NHID 1024
#define BATCH 2048
#define CAP 256      // bucket capacity per class (mean ~9.1)
#define LSTRIDE 256  // logits ws row stride (floats)

// blogits geometry (register path, HBM-streamed weights)
#define NCHUNK 8     // d-chunks per row
#define CHUNK_D 128  // NHID / NCHUNK
#define NDQ 32       // CHUNK_D / 4

// tlogits geometry (LDS-staged weights) — proven R8/R9 structure
#define TCH 16       // d-chunks
#define TCH_D 64     // d per chunk
#define TROWS 32     // rows per block (8 waves x 4)
#define TPAD 228     // padded LDS row stride (dwords)

// ---------------------------------------------------------------------------
// Kernel 1: bucket examples by class. Single block, LDS atomics.
// ---------------------------------------------------------------------------
__global__ __launch_bounds__(256) void hs_bucket(const int* __restrict__ labels,
                                                 int* __restrict__ bucket,
                                                 int* __restrict__ cnt) {
    __shared__ int scnt[NCLS];
    const int t = threadIdx.x;
    for (int i = t; i < NCLS; i += 256) scnt[i] = 0;
    __syncthreads();
    for (int b = t; b < BATCH; b += 256) {
        int lab = labels[b];
        int c = lab / TPC;
        int pos = atomicAdd(&scnt[c], 1);
        bucket[c * CAP + pos] = b;
    }
    __syncthreads();
    for (int i = t; i < NCLS; i += 256) cnt[i] = scnt[i];
}

// ---------------------------------------------------------------------------
// Kernel 2: top logits, LDS-staged weights (R8/R9 structure, verbatim —
// cross-round ledger: "rest" fell ~45 us when this replaced register tlogits).
// Grid = 64 row-tiles x 16 chunks; 512 thr = 8 waves x 4 rows.
// ---------------------------------------------------------------------------
__global__ __launch_bounds__(512, 2) void hs_tlogits(const float* __restrict__ x,
                                                     const float* __restrict__ W,
                                                     float* __restrict__ twsP) {
    __shared__ float lw[TCH_D * TPAD];  // 58368 B -> 2 blocks/CU
    const int rb = blockIdx.x >> 4;  // row-tile 0..63
    const int q = blockIdx.x & 15;   // d-chunk 0..15
    const int t = threadIdx.x;
    const int lane = t & 63;
    const int wv = t >> 6;           // wave 0..7

    for (int r = wv; r < TCH_D; r += 8) {
        if (lane < 56) {
            float4 v = *(const float4*)(W + (size_t)(q * TCH_D + r) * NCLS + 4 * lane);
            *(float4*)(&lw[r * TPAD + 4 * lane]) = v;
        }
    }
    __syncthreads();

    int rows[4];
#pragma unroll
    for (int rl = 0; rl < 4; rl++) rows[rl] = rb * TROWS + wv * 4 + rl;
    const float* xp[4];
#pragma unroll
    for (int rl = 0; rl < 4; rl++)
        xp[rl] = x + (size_t)rows[rl] * NHID + q * TCH_D;
    int kcl[4];
#pragma unroll
    for (int j = 0; j < 4; j++) {
        int k = lane + 64 * j;
        kcl[j] = (k < NCLS) ? k : (NCLS - 1);
    }

    float acc[4][4] = {};
    for (int dq = 0; dq < TCH_D / 4; ++dq) {  // 16
        float w[4][4];
#pragma unroll
        for (int di = 0; di < 4; di++)
#pragma unroll
            for (int j = 0; j < 4; j++)
                w[di][j] = lw[(dq * 4 + di) * TPAD + kcl[j]];
        float4 xq[4];
#pragma unroll
        for (int rl = 0; rl < 4; rl++)
            xq[rl] = *(const float4*)(xp[rl] + dq * 4);
#pragma unroll
        for (int rl = 0; rl < 4; rl++)
#pragma unroll
            for (int di = 0; di < 4; di++) {
                float xv = ((const float*)&xq[rl])[di];
#pragma unroll
                for (int j = 0; j < 4; j++)
                    acc[rl][j] = fmaf(xv, w[di][j], acc[rl][j]);
            }
    }

    float* tp = twsP + (size_t)q * BATCH * LSTRIDE;
#pragma unroll
    for (int rl = 0; rl < 4; rl++)
#pragma unroll
        for (int j = 0; j < 4; j++) {
            int k = lane + 64 * j;
            if (k < NCLS) tp[(size_t)rows[rl] * LSTRIDE + k] = acc[rl][j];
        }
}

// ---------------------------------------------------------------------------
// Kernel 3: bottom logits. EXACT R4 inner body (the only spill-free register
// variant: 64 VGPR; R3/R5/R6/R8 alternatives all spilled or regressed) but
// in 512-thread blocks = 8 waves — doubling per-block wave count to test the
// residency ceiling (R4: 33% occupancy = ~10.6 waves/CU vs ~21 needed to
// hide the ~900cy weight-load latency). (512,2): VGPR cap 256 -> no spill.
// Rows interleaved idx = base + wv + 8*rl for class-imbalance balance.
// ---------------------------------------------------------------------------
#define LOADW(W)                                              \
    do {                                                      \
        _Pragma("unroll") for (int di = 0; di < 4; di++)      \
            _Pragma("unroll") for (int j = 0; j < 4; j++)     \
                W[di][j] = pj[j][di * TPC];                   \
        _Pragma("unroll") for (int j = 0; j < 4; j++)         \
            pj[j] += 4 * TPC;                                 \
    } while (0)

#define LOADX(X, dq)                                          \
    do {                                                      \
        _Pragma("unroll") for (int rl = 0; rl < RW; rl++)     \
            X[rl] = *(const float4*)(xp[rl] + (dq) * 4);      \
    } while (0)

#define FMAS(W, X)                                            \
    do {                                                      \
        _Pragma("unroll") for (int rl = 0; rl < RW; rl++) {   \
            _Pragma("unroll") for (int di = 0; di < 4; di++) {\
                float xv = ((const float*)&X[rl])[di];        \
                _Pragma("unroll") for (int j = 0; j < 4; j++) \
                    acc[rl][j] = fmaf(xv, W[di][j], acc[rl][j]); \
            }                                                 \
        }                                                     \
    } while (0)

template <int RW>
__device__ __forceinline__ void bchunk(const float* __restrict__ xb,
                                       const float* __restrict__ wq,
                                       const int* __restrict__ bucket_c,
                                       const int base, const int n,
                                       const int lane, const int wv,
                                       float* __restrict__ bp) {
    int rows[RW], rval[RW];
#pragma unroll
    for (int rl = 0; rl < RW; rl++) {
        int idx = base + wv + 8 * rl;  // interleaved for balance
        rows[rl] = bucket_c[idx < n ? idx : 0];  // pad rows alias entry 0
        rval[rl] = (idx < n);
    }
    const float* xp[RW];
#pragma unroll
    for (int rl = 0; rl < RW; rl++) xp[rl] = xb + (size_t)rows[rl] * NHID;
    const float* pj[4];
#pragma unroll
    for (int j = 0; j < 4; j++) {
        int k = 64 * j + lane;
        pj[j] = wq + (k < TPC ? k : TPC - 1);
    }
    float acc[RW][4];
#pragma unroll
    for (int rl = 0; rl < RW; rl++)
#pragma unroll
        for (int j = 0; j < 4; j++) acc[rl][j] = 0.f;

    float wA[4][4], wB[4][4];
    float4 xA[RW], xB[RW];
    LOADW(wA);
    LOADX(xA, 0);
    for (int dq = 0; dq < NDQ; dq += 2) {
        LOADW(wB);                  // prefetch dq+1 weights
        LOADX(xB, dq + 1);
        FMAS(wA, xA);               // compute dq
        if (dq + 2 < NDQ) {
            LOADW(wA);              // prefetch dq+2
            LOADX(xA, dq + 2);
        }
        FMAS(wB, xB);               // compute dq+1
    }
#pragma unroll
    for (int rl = 0; rl < RW; rl++) {
        if (rval[rl]) {
#pragma unroll
            for (int j = 0; j < 4; j++) {
                int k = 64 * j + lane;
                if (k < TPC) bp[(size_t)rows[rl] * LSTRIDE + k] = acc[rl][j];
            }
        }
    }
}

__global__ __launch_bounds__(512, 2) void hs_blogits(const float* __restrict__ x,
                                                     const float* __restrict__ Wb,
                                                     const int* __restrict__ bucket,
                                                     const int* __restrict__ cnt,
                                                     float* __restrict__ bws) {
    const int c = blockIdx.x >> 3;  // class
    const int q = blockIdx.x & 7;   // d-chunk
    const int n = cnt[c];
    if (n == 0) return;
    const int lane = threadIdx.x & 63;
    const int wv = threadIdx.x >> 6;  // wave 0..7
    const float* wq = Wb + (size_t)c * (NHID * TPC) + (size_t)q * CHUNK_D * TPC;
    const float* xb = x + q * CHUNK_D;
    const int* bucket_c = bucket + c * CAP;
    float* bp = bws + (size_t)q * BATCH * LSTRIDE;

    for (int base = 0; base < n; base += 32) {  // 8 waves x up to 4 rows
        int m = n - base;
        if (m > 32) m = 32;
        const int RW = (m + 7) >> 3;  // rows per wave, block-uniform
        switch (RW) {
            case 1: bchunk<1>(xb, wq, bucket_c, base, n, lane, wv, bp); break;
            case 2: bchunk<2>(xb, wq, bucket_c, base, n, lane, wv, bp); break;
            case 3: bchunk<3>(xb, wq, bucket_c, base, n, lane, wv, bp); break;
            default: bchunk<4>(xb, wq, bucket_c, base, n, lane, wv, bp); break;
        }
    }
}

// ---------------------------------------------------------------------------
// Kernel 4: finish. One wave per row: sum partials (16 top, 8 bottom),
// softmax, out = p_cls * p_word.
// ---------------------------------------------------------------------------
__global__ __launch_bounds__(256) void hs_finish(const float* __restrict__ tws,
                                                 const float* __restrict__ bws,
                                                 const int* __restrict__ labels,
                                                 const float* __restrict__ b_top,
                                                 const float* __restrict__ b_bot,
                                                 float* __restrict__ out) {
    const int lane = threadIdx.x & 63;
    const int wave = threadIdx.x >> 6;
    const int row = blockIdx.x * 4 + wave;
    const int label = labels[row];
    const int c = label / TPC;
    const int word = label - c * TPC;

    float p[2];
#pragma unroll
    for (int lvl = 0; lvl < 2; lvl++) {
        const int NS = lvl ? TPC : NCLS;
        const int NP = lvl ? NCHUNK : TCH;
        const int pick = lvl ? word : c;
        const float* lws = lvl ? bws : tws;
        const float* bias = lvl ? (b_bot + c * TPC) : b_top;
        float lg[4];
#pragma unroll
        for (int j = 0; j < 4; j++) {
            int k = lane + 64 * j;
            if (k < NS) {
                float v = 0.f;
                for (int pq = 0; pq < NP; pq++)
                    v += lws[((size_t)pq * BATCH + row) * LSTRIDE + k];
                lg[j] = v + bias[k];
            } else {
                lg[j] = -INFINITY;
            }
        }
        float m = fmaxf(fmaxf(lg[0], lg[1]), fmaxf(lg[2], lg[3]));
#pragma unroll
        for (int off = 32; off > 0; off >>= 1) m = fmaxf(m, __shfl_xor(m, off, 64));
        float s = 0.f, pp = 0.f;
#pragma unroll
        for (int j = 0; j < 4; j++) {
            int k = lane + 64 * j;
            float e = (k < NS) ? __expf(lg[j] - m) : 0.f;
            s += e;
            if (k == pick) pp = e;
        }
#pragma unroll
        for (int off = 32; off > 0; off >>= 1) {
            s += __shfl_xor(s, off, 64);
            pp += __shfl_xor(pp, off, 64);
        }
        p[lvl] = pp / s;
    }
    if (lane == 0) out[row] = p[0] * p[1];
}

// ---------------------------------------------------------------------------
extern "C" void kernel_launch(void* const* d_in, const int* in_sizes, int n_in,
                              void* d_out, int out_size, void* d_ws, size_t ws_size,
                              hipStream_t stream) {
    const float* inputs   = (const float*)d_in[0];
    const int*   labels   = (const int*)d_in[1];
    const float* W_top    = (const float*)d_in[2];
    const float* b_top    = (const float*)d_in[3];
    const float* W_bottom = (const float*)d_in[4];
    const float* b_bottom = (const float*)d_in[5];
    float* out = (float*)d_out;

    // ws: bucket[NCLS*CAP] | cnt[NCLS] | tws[16*B*LSTRIDE] | bws[8*B*LSTRIDE]
    int* bucket = (int*)d_ws;
    int* cnt    = bucket + NCLS * CAP;
    float* tws  = (float*)(cnt + NCLS);
    float* bws  = tws + (size_t)TCH * BATCH * LSTRIDE;

    hs_bucket<<<1, 256, 0, stream>>>(labels, bucket, cnt);
    hs_tlogits<<<64 * TCH, 512, 0, stream>>>(inputs, W_top, tws);
    hs_blogits<<<NCLS * NCHUNK, 512, 0, stream>>>(inputs, W_bottom, bucket, cnt, bws);
    hs_finish<<<BATCH / 4, 256, 0, stream>>>(tws, bws, labels, b_top, b_bottom, out);
}